// Round 1
// baseline (331.665 us; speedup 1.0000x reference)
//
#include <hip/hip_runtime.h>
#include <math.h>

#define DIM 480          // 128*1 + 64*3 + 32*5
#define BLOCK 256

// scaling = silu(max(n,eps))/max(n,eps) == sigmoid(max(n,eps))
__device__ __forceinline__ float sig_scale(float ss) {
    float n = fmaxf(sqrtf(ss), 1e-8f);
    return 1.0f / (1.0f + __expf(-n));
}

// Chunk decomposition (all float4-aligned, 4 complete groups per chunk):
//   region A: 128 x 0e -> 32 chunks/row, 1 float4 each  (4 singleton groups)
//   region B:  64 x 1o -> 16 chunks/row, 3 float4 each  (4 groups of 3)
//   region C:  32 x 2e ->  8 chunks/row, 5 float4 each  (4 groups of 5)
// One thread = one chunk, fully in registers. No LDS, no barriers.
__global__ __launch_bounds__(BLOCK) void norm_act_kernel(
    const float* __restrict__ in, float* __restrict__ out,
    int nA, int nAB, int total)
{
    const int t = blockIdx.x * BLOCK + threadIdx.x;
    if (t >= total) return;

    if (t < nA) {
        // ---- region A: 1 float4 = 4 d=1 groups; norm = |x| ----
        const int row = t >> 5;
        const int ci  = t & 31;
        const size_t off = (size_t)row * DIM + (size_t)ci * 4;
        float4 x = *(const float4*)(in + off);
        x.x *= sig_scale(x.x * x.x);
        x.y *= sig_scale(x.y * x.y);
        x.z *= sig_scale(x.z * x.z);
        x.w *= sig_scale(x.w * x.w);
        *(float4*)(out + off) = x;
    } else if (t < nAB) {
        // ---- region B: 3 float4 = 12 floats = 4 d=3 groups ----
        const int i   = t - nA;
        const int row = i >> 4;
        const int ci  = i & 15;
        const size_t off = (size_t)row * DIM + 128 + (size_t)ci * 12;
        const float4* p = (const float4*)(in + off);
        float4 a = p[0], b = p[1], c = p[2];
        const float s0 = sig_scale(a.x*a.x + a.y*a.y + a.z*a.z);
        const float s1 = sig_scale(a.w*a.w + b.x*b.x + b.y*b.y);
        const float s2 = sig_scale(b.z*b.z + b.w*b.w + c.x*c.x);
        const float s3 = sig_scale(c.y*c.y + c.z*c.z + c.w*c.w);
        a.x *= s0; a.y *= s0; a.z *= s0; a.w *= s1;
        b.x *= s1; b.y *= s1; b.z *= s2; b.w *= s2;
        c.x *= s2; c.y *= s3; c.z *= s3; c.w *= s3;
        float4* q = (float4*)(out + off);
        q[0] = a; q[1] = b; q[2] = c;
    } else {
        // ---- region C: 5 float4 = 20 floats = 4 d=5 groups ----
        const int i   = t - nAB;
        const int row = i >> 3;
        const int ci  = i & 7;
        const size_t off = (size_t)row * DIM + 320 + (size_t)ci * 20;
        const float4* p = (const float4*)(in + off);
        float4 a = p[0], b = p[1], c = p[2], d = p[3], e = p[4];
        const float s0 = sig_scale(a.x*a.x + a.y*a.y + a.z*a.z + a.w*a.w + b.x*b.x);
        const float s1 = sig_scale(b.y*b.y + b.z*b.z + b.w*b.w + c.x*c.x + c.y*c.y);
        const float s2 = sig_scale(c.z*c.z + c.w*c.w + d.x*d.x + d.y*d.y + d.z*d.z);
        const float s3 = sig_scale(d.w*d.w + e.x*e.x + e.y*e.y + e.z*e.z + e.w*e.w);
        a.x *= s0; a.y *= s0; a.z *= s0; a.w *= s0;
        b.x *= s0; b.y *= s1; b.z *= s1; b.w *= s1;
        c.x *= s1; c.y *= s1; c.z *= s2; c.w *= s2;
        d.x *= s2; d.y *= s2; d.z *= s2; d.w *= s3;
        e.x *= s3; e.y *= s3; e.z *= s3; e.w *= s3;
        float4* q = (float4*)(out + off);
        q[0] = a; q[1] = b; q[2] = c; q[3] = d; q[4] = e;
    }
}

extern "C" void kernel_launch(void* const* d_in, const int* in_sizes, int n_in,
                              void* d_out, int out_size, void* d_ws, size_t ws_size,
                              hipStream_t stream) {
    const float* in  = (const float*)d_in[0];
    float*       out = (float*)d_out;
    const int n_rows = in_sizes[0] / DIM;        // 100000
    const int nA     = n_rows * 32;              // A chunks
    const int nAB    = nA + n_rows * 16;         // A + B chunks
    const int total  = nAB + n_rows * 8;         // + C chunks = 56/row
    const int grid   = (total + BLOCK - 1) / BLOCK;
    norm_act_kernel<<<grid, BLOCK, 0, stream>>>(in, out, nA, nAB, total);
}

// Round 2
// 319.247 us; speedup vs baseline: 1.0389x; 1.0389x over previous
//
#include <hip/hip_runtime.h>
#include <math.h>

#define DIM 480          // 128*1 + 64*3 + 32*5
#define ROWS 8           // rows per wave
#define BLOCK 64         // one wave per block: no __syncthreads anywhere
#define NLOADS 15        // ROWS*DIM*4B / 1024B  (15 x 1KB global_load_lds)

// scaling = silu(max(n,eps))/max(n,eps) == sigmoid(max(n,eps))
__device__ __forceinline__ float sig_of(float n) {
    n = fmaxf(n, 1e-8f);
    return __builtin_amdgcn_rcpf(1.0f + __expf(-n));
}

// Scale all groups of `rows` rows in-place in LDS.
// Bank analysis (32 banks, row stride 480 floats == 0 mod 32):
//   A: unit stride across lanes -> conflict-free
//   B: stride 3 (gcd(3,32)=1)   -> 2-way max (free, m136)
//   C: stride 5 (gcd(5,32)=1)   -> 2-way max (free)
template <int R>
__device__ __forceinline__ void scale_groups(float* sbuf, int lane) {
    // region A: R*128 d=1 groups; norm = |x| (no sqrt needed)
    #pragma unroll
    for (int k = 0; k < R * 2; ++k) {
        const int a = k * 64 + lane;
        float* p = sbuf + (a >> 7) * DIM + (a & 127);
        const float x = *p;
        *p = x * sig_of(fabsf(x));
    }
    // region B: R*64 d=3 groups
    #pragma unroll
    for (int k = 0; k < R; ++k) {
        const int b = k * 64 + lane;
        float* p = sbuf + (b >> 6) * DIM + 128 + 3 * (b & 63);
        const float x0 = p[0], x1 = p[1], x2 = p[2];
        const float s = sig_of(sqrtf(x0*x0 + x1*x1 + x2*x2));
        p[0] = x0 * s; p[1] = x1 * s; p[2] = x2 * s;
    }
    // region C: R*32 d=5 groups
    #pragma unroll
    for (int k = 0; k < R / 2; ++k) {
        const int c = k * 64 + lane;
        float* p = sbuf + (c >> 5) * DIM + 320 + 5 * (c & 31);
        const float x0 = p[0], x1 = p[1], x2 = p[2], x3 = p[3], x4 = p[4];
        const float s = sig_of(sqrtf(x0*x0 + x1*x1 + x2*x2 + x3*x3 + x4*x4));
        p[0] = x0*s; p[1] = x1*s; p[2] = x2*s; p[3] = x3*s; p[4] = x4*s;
    }
}

__device__ void scale_groups_rt(float* sbuf, int lane, int rows) {
    for (int a = lane; a < rows * 128; a += 64) {
        float* p = sbuf + (a >> 7) * DIM + (a & 127);
        const float x = *p;
        *p = x * sig_of(fabsf(x));
    }
    for (int b = lane; b < rows * 64; b += 64) {
        float* p = sbuf + (b >> 6) * DIM + 128 + 3 * (b & 63);
        const float x0 = p[0], x1 = p[1], x2 = p[2];
        const float s = sig_of(sqrtf(x0*x0 + x1*x1 + x2*x2));
        p[0] = x0 * s; p[1] = x1 * s; p[2] = x2 * s;
    }
    for (int c = lane; c < rows * 32; c += 64) {
        float* p = sbuf + (c >> 5) * DIM + 320 + 5 * (c & 31);
        const float x0 = p[0], x1 = p[1], x2 = p[2], x3 = p[3], x4 = p[4];
        const float s = sig_of(sqrtf(x0*x0 + x1*x1 + x2*x2 + x3*x3 + x4*x4));
        p[0] = x0*s; p[1] = x1*s; p[2] = x2*s; p[3] = x3*s; p[4] = x4*s;
    }
}

__global__ __launch_bounds__(BLOCK) void norm_act_kernel(
    const float* __restrict__ in, float* __restrict__ out, int n_rows)
{
    __shared__ __align__(16) float sbuf[ROWS * DIM];   // 15360 B -> 10 blocks/CU
    const int lane = threadIdx.x;
    const int row0 = blockIdx.x * ROWS;
    const int rows = min(ROWS, n_rows - row0);

    const float* gsrc = in  + (size_t)row0 * DIM;
    float*       gdst = out + (size_t)row0 * DIM;

    if (rows == ROWS) {
        // ---- stage: 15 x 1KB coalesced direct-to-LDS (no VGPR round-trip) ----
        #pragma unroll
        for (int k = 0; k < NLOADS; ++k) {
            const float* gp = gsrc + (size_t)(k * 64 + lane) * 4;  // per-lane 16B
            __builtin_amdgcn_global_load_lds(
                (const __attribute__((address_space(1))) void*)gp,
                (__attribute__((address_space(3))) void*)((char*)sbuf + k * 1024),
                16, 0, 0);
        }
        asm volatile("s_waitcnt vmcnt(0)" ::: "memory");  // wave-local; no barrier

        // ---- compute: in-place group scaling in LDS ----
        scale_groups<ROWS>(sbuf, lane);

        // ---- drain: coalesced ds_read_b128 -> global_store_dwordx4 ----
        #pragma unroll
        for (int k = 0; k < NLOADS; ++k) {
            const int v = k * 64 + lane;
            ((float4*)gdst)[v] = ((const float4*)sbuf)[v];
        }
    } else if (rows > 0) {
        // tail block (not hit for n_rows=100000): plain staging, runtime bounds
        for (int v = lane; v < rows * (DIM / 4); v += BLOCK)
            ((float4*)sbuf)[v] = ((const float4*)gsrc)[v];
        scale_groups_rt(sbuf, lane, rows);
        for (int v = lane; v < rows * (DIM / 4); v += BLOCK)
            ((float4*)gdst)[v] = ((const float4*)sbuf)[v];
    }
}

extern "C" void kernel_launch(void* const* d_in, const int* in_sizes, int n_in,
                              void* d_out, int out_size, void* d_ws, size_t ws_size,
                              hipStream_t stream) {
    const float* in  = (const float*)d_in[0];
    float*       out = (float*)d_out;
    const int n_rows = in_sizes[0] / DIM;                  // 100000
    const int grid   = (n_rows + ROWS - 1) / ROWS;         // 12500 wave-blocks
    norm_act_kernel<<<grid, BLOCK, 0, stream>>>(in, out, n_rows);
}